// Round 5
// baseline (917.189 us; speedup 1.0000x reference)
//
#include <hip/hip_runtime.h>
#include <math.h>

#define N_NODES 50000
#define N_EDGES 800000
#define NB 25              // src buckets (src >> 11, 2048 nodes -> 1.76 MB of h each)
#define NPAD 50176         // nodes rounded to x256
#define NKEY (NB * NPAD)   // 1254400 keys: key = (src>>11)*NPAD + dst

typedef __attribute__((ext_vector_type(8))) short short8;
typedef __attribute__((ext_vector_type(4))) float f32x4;

// ---------------- CSR build (bucket-major, cursorless) ----------------

__global__ void k_hist(const int* __restrict__ ei, int* __restrict__ deg_out,
                       int* __restrict__ ecs) {
    int e = blockIdx.x * 256 + threadIdx.x;
    if (e < N_EDGES) {
        int s = ei[e], d = ei[N_EDGES + e];
        atomicAdd(&deg_out[s], 1);
        atomicAdd(&ecs[(s >> 11) * NPAD + d], 1);
    }
}

// exclusive scan, 256-blocks (in-place safe: in[i] read before any write)
__global__ void k_scan1(const int* __restrict__ in, int* __restrict__ out,
                        int* __restrict__ bsum, int n) {
    __shared__ int s[256];
    int i = blockIdx.x * 256 + threadIdx.x;
    int v = (i < n) ? in[i] : 0;
    s[threadIdx.x] = v;
    __syncthreads();
    for (int off = 1; off < 256; off <<= 1) {
        int t = (threadIdx.x >= off) ? s[threadIdx.x - off] : 0;
        __syncthreads();
        s[threadIdx.x] += t;
        __syncthreads();
    }
    if (i < n) out[i] = s[threadIdx.x] - v;
    if (threadIdx.x == 255 && bsum) bsum[blockIdx.x] = s[255];
}

__global__ void k_scan3(int* __restrict__ out, const int* __restrict__ bscan, int n) {
    int i = blockIdx.x * 256 + threadIdx.x;
    if (i < n) out[i] += bscan[blockIdx.x];
}

// after scan, before bucket-fill: deg_in(n) = sum_b (ecs[b*NPAD+n+1]-ecs[b*NPAD+n])
__global__ void k_invsqrt(const int* __restrict__ deg_out, const int* __restrict__ ecs,
                          float* __restrict__ inv_out, float* __restrict__ inv_in) {
    int n = blockIdx.x * 256 + threadIdx.x;
    if (n >= N_NODES) return;
    int di = 0;
#pragma unroll
    for (int b = 0; b < NB; ++b) di += ecs[b * NPAD + n + 1] - ecs[b * NPAD + n];
    int a = deg_out[n]; if (a < 1) a = 1;
    if (di < 1) di = 1;
    inv_out[n] = 1.0f / sqrtf((float)a);
    inv_in[n]  = 1.0f / sqrtf((float)di);
}

// atomic on ecs doubles as cursor; post-fill range(key) = [ecs[key-1], ecs[key])
__global__ void k_bucket(const int* __restrict__ ei, int* __restrict__ ecs,
                         int* __restrict__ src_sorted) {
    int e = blockIdx.x * 256 + threadIdx.x;
    if (e < N_EDGES) {
        int s = ei[e], d = ei[N_EDGES + e];
        int p = atomicAdd(&ecs[(s >> 11) * NPAD + d], 1);
        src_sorted[p] = s;
    }
}

// ---------------- helpers ----------------

__device__ __forceinline__ float fast_tanh(float x) {
    float e = __expf(2.0f * x);
    float r = __builtin_amdgcn_rcpf(e + 1.0f);
    return 1.0f - 2.0f * r;
}

__device__ __forceinline__ unsigned short rne_bf16(float x) {
    unsigned u = __builtin_bit_cast(unsigned, x);
    return (unsigned short)((u + 0x7FFFu + ((u >> 16) & 1u)) >> 16);
}

__device__ __forceinline__ void split_bf16(float x, unsigned short& hi, unsigned short& lo) {
    hi = rne_bf16(x);
    float hf = __builtin_bit_cast(float, (unsigned)hi << 16);
    lo = rne_bf16(x - hf);
}

__device__ __forceinline__ f32x4 mfma16(short8 a, short8 b, f32x4 c) {
    return __builtin_amdgcn_mfma_f32_16x16x32_bf16(a, b, c, 0, 0, 0);
}

// ---------------- aggregation ----------------

// layer 0: gather x*inv_out (width 22), *inv_in, split to bf16 A (K padded to 32).
// 16 threads/node (f2 = 0..15 float2 slots; slots 11..15 are zero K-pad).
__global__ void k_agg22_split(const float* __restrict__ x, const float* __restrict__ inv_out,
                              const int* __restrict__ ecs, const int* __restrict__ srcs,
                              const float* __restrict__ inv_in,
                              unsigned short* __restrict__ A_hi, unsigned short* __restrict__ A_lo) {
    int idx = blockIdx.x * 256 + threadIdx.x;
    int n = idx >> 4, f2 = idx & 15;
    if (n >= N_NODES) return;
    float ax = 0.f, ay = 0.f;
    if (f2 <= 10) {
        const float2* xb = (const float2*)(x) + f2;   // &x[s*22 + f2*2] = xb[s*11]
        for (int b = 0; b < NB; ++b) {
            int key = b * NPAD + n;
            int lo = (key > 0) ? ecs[key - 1] : 0;
            int hi = ecs[key];
            for (int e = lo; e < hi; ++e) {
                int s = srcs[e];
                float sc = inv_out[s];
                float2 v = xb[s * 11];
                ax += v.x * sc;
                ay += v.y * sc;
            }
        }
        float si = inv_in[n];
        ax *= si; ay *= si;
    }
    ushort2 h2, l2;
    split_bf16(ax, h2.x, l2.x);
    split_bf16(ay, h2.y, l2.y);
    *(ushort2*)&A_hi[n * 32 + f2 * 2] = h2;
    *(ushort2*)&A_lo[n * 32 + f2 * 2] = l2;
}

// width-220 gather + fused (sum*inv_in) -> split bf16 A (stride 224, cols 220..223 = 0).
// 32 nodes per 256-block, 1563 blocks -> entire grid co-resident, so all blocks
// walk src-buckets 0..24 roughly in phase: concurrently-touched h slice ~2-3
// buckets (~5 MB) -> per-XCD L2-resident (round 4: 44 MB random -> 50% miss).
__global__ __launch_bounds__(256, 6) void k_agg220_split(const float* __restrict__ h,
                                                         const int* __restrict__ ecs,
                                                         const int* __restrict__ srcs,
                                                         const float* __restrict__ inv_in,
                                                         unsigned short* __restrict__ A_hi,
                                                         unsigned short* __restrict__ A_lo) {
    int lane = threadIdx.x & 63;
    int nbase = blockIdx.x * 32 + (threadIdx.x >> 6) * 8;
    bool act = lane < 55;
    int f4 = lane * 4;
    const float* hb = h + f4;
    float4 acc[8];
#pragma unroll
    for (int i = 0; i < 8; ++i) acc[i] = (float4){0.f, 0.f, 0.f, 0.f};

    for (int b = 0; b < NB; ++b) {
        int kb = b * NPAD + nbase;
#pragma unroll
        for (int i = 0; i < 8; ++i) {
            int n = nbase + i;
            if (n >= N_NODES) continue;
            int key = kb + i;
            int lo = (key > 0) ? ecs[key - 1] : 0;
            int hi = ecs[key];
            for (int e = lo; e < hi; ++e) {
                int s = srcs[e];
                if (act) {
                    float4 v = *(const float4*)&hb[s * 220];
                    acc[i].x += v.x; acc[i].y += v.y; acc[i].z += v.z; acc[i].w += v.w;
                }
            }
        }
    }
#pragma unroll
    for (int i = 0; i < 8; ++i) {
        int n = nbase + i;
        if (n >= N_NODES) continue;
        size_t ob = (size_t)n * 224 + f4;
        if (act) {
            float sc = inv_in[n];
            ushort4 h4, l4;
            split_bf16(acc[i].x * sc, h4.x, l4.x);
            split_bf16(acc[i].y * sc, h4.y, l4.y);
            split_bf16(acc[i].z * sc, h4.z, l4.z);
            split_bf16(acc[i].w * sc, h4.w, l4.w);
            *(ushort4*)&A_hi[ob] = h4;
            *(ushort4*)&A_lo[ob] = l4;
        } else if (lane == 55) {
            ushort4 z = {0, 0, 0, 0};
            *(ushort4*)&A_hi[ob] = z;
            *(ushort4*)&A_lo[ob] = z;
        }
    }
}

// layer 3: gather tmp10 (width 10), epilogue *inv_in + bias, straight to d_out.
// 5 threads/node, float2.
__global__ void k_agg10_epi(const float* __restrict__ tmp, const int* __restrict__ ecs,
                            const int* __restrict__ srcs, const float* __restrict__ inv_in,
                            const float* __restrict__ bias, float* __restrict__ out) {
    int idx = blockIdx.x * 256 + threadIdx.x;
    if (idx >= N_NODES * 5) return;
    int n = idx / 5;
    int f2 = idx - n * 5;
    const float2* tb = (const float2*)(tmp) + f2;
    float ax = 0.f, ay = 0.f;
    for (int b = 0; b < NB; ++b) {
        int key = b * NPAD + n;
        int lo = (key > 0) ? ecs[key - 1] : 0;
        int hi = ecs[key];
        for (int e = lo; e < hi; ++e) {
            float2 v = tb[srcs[e] * 5];
            ax += v.x;
            ay += v.y;
        }
    }
    float si = inv_in[n];
    float2 o;
    o.x = ax * si + bias[f2 * 2];
    o.y = ay * si + bias[f2 * 2 + 1];
    *(float2*)&out[n * 10 + f2 * 2] = o;
}

// ---------------- weight split ----------------
// W [KIN x 220 fp32] -> WT_hi/lo [224 n][LDA k] bf16, transposed + zero-padded
template <int KIN, int LDA>
__global__ void k_wsplit(const float* __restrict__ W, unsigned short* __restrict__ WT_hi,
                         unsigned short* __restrict__ WT_lo) {
    int idx = blockIdx.x * 256 + threadIdx.x;
    if (idx >= 224 * LDA) return;
    int n = idx / LDA;
    int k = idx - n * LDA;
    float v = (n < 220 && k < KIN) ? W[k * 220 + n] : 0.f;
    unsigned short hi, lo;
    split_bf16(v, hi, lo);
    WT_hi[idx] = hi;
    WT_lo[idx] = lo;
}

// ---------------- MFMA split-bf16 GEMM ----------------
// D = A@W to ~fp32 precision via A_hi*W_hi + A_hi*W_lo + A_lo*W_hi.
// out[n][j] = post[n] * tanh(D[n][j] + bias[j]);  inv_in pre-folded into A.
// Wave = 16 rows x 224 cols; no LDS, no barriers; frags are direct dwordx4 loads.
template <int KSTEPS, int LDA>
__global__ __launch_bounds__(256) void k_gemm_mfma(const unsigned short* __restrict__ A_hi,
                                                   const unsigned short* __restrict__ A_lo,
                                                   const unsigned short* __restrict__ WT_hi,
                                                   const unsigned short* __restrict__ WT_lo,
                                                   const float* __restrict__ bias,
                                                   const float* __restrict__ post,
                                                   float* __restrict__ out) {
    int tid = threadIdx.x;
    int l = tid & 63, w = tid >> 6;
    int lrow = l & 15, q = l >> 4;
    int rtile = blockIdx.x * 64 + w * 16;

    const unsigned short* pah = A_hi + (size_t)(rtile + lrow) * LDA + q * 8;
    const unsigned short* pal = A_lo + (size_t)(rtile + lrow) * LDA + q * 8;

    f32x4 acc[14];
#pragma unroll
    for (int ct = 0; ct < 14; ++ct) acc[ct] = (f32x4){0.f, 0.f, 0.f, 0.f};

#pragma unroll
    for (int ks = 0; ks < KSTEPS; ++ks) {
        int k0 = ks * 32;
        short8 ah = *(const short8*)(const void*)(pah + k0);
        short8 al = *(const short8*)(const void*)(pal + k0);
#pragma unroll
        for (int ct = 0; ct < 14; ++ct) {
            size_t boff = (size_t)(ct * 16 + lrow) * LDA + q * 8 + k0;
            short8 bh = *(const short8*)(const void*)(WT_hi + boff);
            short8 bl = *(const short8*)(const void*)(WT_lo + boff);
            acc[ct] = mfma16(ah, bh, acc[ct]);
            acc[ct] = mfma16(ah, bl, acc[ct]);
            acc[ct] = mfma16(al, bh, acc[ct]);
        }
    }

    float pv[4];
#pragma unroll
    for (int r = 0; r < 4; ++r) {
        int row = rtile + q * 4 + r;
        pv[r] = (row < N_NODES) ? post[row] : 0.f;
    }
#pragma unroll
    for (int ct = 0; ct < 14; ++ct) {
        int col = ct * 16 + lrow;
        if (col >= 220) continue;
        float bv = bias[col];
#pragma unroll
        for (int r = 0; r < 4; ++r) {
            int row = rtile + q * 4 + r;
            if (row < N_NODES)
                out[(size_t)row * 220 + col] = pv[r] * fast_tanh(acc[ct][r] + bv);
        }
    }
}

// tmp10 = h @ W3
__global__ void k_w3(const float* __restrict__ h, const float* __restrict__ W3,
                     float* __restrict__ tmp) {
    int idx = blockIdx.x * 256 + threadIdx.x;
    if (idx >= N_NODES * 10) return;
    int n = idx / 10;
    int j = idx - n * 10;
    const float2* hr = (const float2*)&h[n * 220];
    float acc = 0.f;
#pragma unroll 10
    for (int k2 = 0; k2 < 110; ++k2) {
        float2 hv = hr[k2];
        acc += hv.x * W3[(2 * k2) * 10 + j];
        acc += hv.y * W3[(2 * k2 + 1) * 10 + j];
    }
    tmp[idx] = acc;
}

// ---------------- launch ----------------

extern "C" void kernel_launch(void* const* d_in, const int* in_sizes, int n_in,
                              void* d_out, int out_size, void* d_ws, size_t ws_size,
                              hipStream_t stream) {
    const float* x  = (const float*)d_in[0];
    const float* W0 = (const float*)d_in[1];
    const float* b0 = (const float*)d_in[2];
    const float* W1 = (const float*)d_in[3];
    const float* b1 = (const float*)d_in[4];
    const float* W2 = (const float*)d_in[5];
    const float* b2 = (const float*)d_in[6];
    const float* W3 = (const float*)d_in[7];
    const float* b3 = (const float*)d_in[8];
    const int*   ei = (const int*)d_in[9];
    float* out = (float*)d_out;

    int* ws = (int*)d_ws;
    // word offsets
    int* deg_out    = ws + 0;              // 50176
    int* ecs        = ws + 50176;          // 1254400
    int* bsumA      = ws + 1304576;        // 4928 (4900 used)
    int* bsumB      = ws + 1309504;        // 64 (20 used)
    float* inv_out  = (float*)(ws + 1309568);
    float* inv_in   = (float*)(ws + 1359744);
    int* src_sorted = ws + 1409920;        // 800000
    unsigned short* wt0h = (unsigned short*)(ws + 2209920);   // 224*32 = 3584 words
    unsigned short* wt0l = (unsigned short*)(ws + 2213504);
    unsigned short* wt1h = (unsigned short*)(ws + 2217088);   // 224*224 = 25088 words
    unsigned short* wt1l = (unsigned short*)(ws + 2242176);
    unsigned short* wt2h = (unsigned short*)(ws + 2267264);
    unsigned short* wt2l = (unsigned short*)(ws + 2292352);
    unsigned short* ahi  = (unsigned short*)(ws + 2317440);   // 50176*224 -> 5619712 words
    unsigned short* alo  = (unsigned short*)(ws + 7937152);   // 5619712 words
    float* tmp10 = (float*)ahi;            // layer-3 alias (ahi dead by then)
    float* hbuf  = (float*)(ws + 13556864); // 50000*220

    // zero deg_out + ecs (adjacent)
    hipMemsetAsync(ws, 0, (size_t)1304576 * sizeof(int), stream);

    // CSR build: hist -> 3-level in-place scan -> invsqrt -> cursorless fill
    k_hist<<<(N_EDGES + 255) / 256, 256, 0, stream>>>(ei, deg_out, ecs);
    k_scan1<<<4900, 256, 0, stream>>>(ecs, ecs, bsumA, NKEY);
    k_scan1<<<20, 256, 0, stream>>>(bsumA, bsumA, bsumB, 4900);
    k_scan1<<<1, 256, 0, stream>>>(bsumB, bsumB, nullptr, 20);
    k_scan3<<<20, 256, 0, stream>>>(bsumA, bsumB, 4900);
    k_scan3<<<4900, 256, 0, stream>>>(ecs, bsumA, NKEY);
    k_invsqrt<<<196, 256, 0, stream>>>(deg_out, ecs, inv_out, inv_in);
    k_bucket<<<(N_EDGES + 255) / 256, 256, 0, stream>>>(ei, ecs, src_sorted);

    // weight splits (independent)
    k_wsplit<22, 32><<<28, 256, 0, stream>>>(W0, wt0h, wt0l);
    k_wsplit<220, 224><<<196, 256, 0, stream>>>(W1, wt1h, wt1l);
    k_wsplit<220, 224><<<196, 256, 0, stream>>>(W2, wt2h, wt2l);

    int mfma_grid = (N_NODES + 63) / 64;     // 782
    int agg_grid  = (N_NODES + 31) / 32;     // 1563 (co-resident)

    // ---- layer 0: gather x at width 22 + split (K pad 32), MFMA GEMM
    k_agg22_split<<<(N_NODES * 16 + 255) / 256, 256, 0, stream>>>(
        x, inv_out, ecs, src_sorted, inv_in, ahi, alo);
    k_gemm_mfma<1, 32><<<mfma_grid, 256, 0, stream>>>(ahi, alo, wt0h, wt0l, b0, inv_out, hbuf);

    // ---- layer 1
    k_agg220_split<<<agg_grid, 256, 0, stream>>>(hbuf, ecs, src_sorted, inv_in, ahi, alo);
    k_gemm_mfma<7, 224><<<mfma_grid, 256, 0, stream>>>(ahi, alo, wt1h, wt1l, b1, inv_out, hbuf);

    // ---- layer 2
    k_agg220_split<<<agg_grid, 256, 0, stream>>>(hbuf, ecs, src_sorted, inv_in, ahi, alo);
    k_gemm_mfma<7, 224><<<mfma_grid, 256, 0, stream>>>(ahi, alo, wt2h, wt2l, b2, inv_out, hbuf);

    // ---- layer 3: GEMM first (width 10), then propagate + epilogue to d_out
    k_w3<<<(N_NODES * 10 + 255) / 256, 256, 0, stream>>>(hbuf, W3, tmp10);
    k_agg10_epi<<<(N_NODES * 5 + 255) / 256, 256, 0, stream>>>(
        tmp10, ecs, src_sorted, inv_in, b3, out);
}

// Round 6
// 810.967 us; speedup vs baseline: 1.1310x; 1.1310x over previous
//
#include <hip/hip_runtime.h>
#include <math.h>

#define N_NODES 50000
#define N_EDGES 800000
#define NB 25              // src buckets (src >> 11): 1.76 MB of h each, per-XCD-L2-sized
#define NPAD 50176         // nodes rounded to x256
#define NKEY (NB * NPAD)   // keys: key = (src>>11)*NPAD + dst
// ecsbuf layout (NKEY+2 ints, ecsbuf[0]=0 forever):
//   counts/prefix/cursor live at ecsbuf[1+key].
//   post-scan  : start(key) = ecsbuf[1+key] (exclusive prefix)
//   post-fill  : ecsbuf[1+key] = end(key), so start(key) = ecsbuf[key], end = ecsbuf[key+1]

typedef __attribute__((ext_vector_type(8))) short short8;
typedef __attribute__((ext_vector_type(4))) float f32x4;

// ---------------- CSR build ----------------

__global__ void k_hist(const int* __restrict__ ei, int* __restrict__ deg_out,
                       int* __restrict__ ecsbuf) {
    int e = blockIdx.x * 256 + threadIdx.x;
    if (e < N_EDGES) {
        int s = ei[e], d = ei[N_EDGES + e];
        atomicAdd(&deg_out[s], 1);
        atomicAdd(&ecsbuf[1 + (s >> 11) * NPAD + d], 1);
    }
}

__global__ void k_scan1(const int* __restrict__ in, int* __restrict__ out,
                        int* __restrict__ bsum, int n) {
    __shared__ int s[256];
    int i = blockIdx.x * 256 + threadIdx.x;
    int v = (i < n) ? in[i] : 0;
    s[threadIdx.x] = v;
    __syncthreads();
    for (int off = 1; off < 256; off <<= 1) {
        int t = (threadIdx.x >= off) ? s[threadIdx.x - off] : 0;
        __syncthreads();
        s[threadIdx.x] += t;
        __syncthreads();
    }
    if (i < n) out[i] = s[threadIdx.x] - v;   // exclusive
    if (threadIdx.x == 255 && bsum) bsum[blockIdx.x] = s[255];
}

// single-block serial-chunk exclusive scan (replaces 3 launches)
__global__ void k_scan_mid(int* __restrict__ a, int n) {
    __shared__ int s[256];
    __shared__ int carry;
    if (threadIdx.x == 0) carry = 0;
    for (int base = 0; base < n; base += 256) {
        int i = base + threadIdx.x;
        int v = (i < n) ? a[i] : 0;
        s[threadIdx.x] = v;
        __syncthreads();
        for (int off = 1; off < 256; off <<= 1) {
            int t = (threadIdx.x >= off) ? s[threadIdx.x - off] : 0;
            __syncthreads();
            s[threadIdx.x] += t;
            __syncthreads();
        }
        int c = carry;
        if (i < n) a[i] = s[threadIdx.x] - v + c;
        __syncthreads();
        if (threadIdx.x == 0) carry = c + s[255];
        __syncthreads();
    }
}

__global__ void k_scan3(int* __restrict__ out, const int* __restrict__ bscan, int n) {
    int i = blockIdx.x * 256 + threadIdx.x;
    if (i < n) out[i] += bscan[blockIdx.x];
}

// pre-fill (exclusive prefix): deg_in(key) = ecsbuf[key+2] - ecsbuf[key+1]
__global__ void k_invsqrt(const int* __restrict__ deg_out, const int* __restrict__ ecsbuf,
                          float* __restrict__ inv_out, float* __restrict__ inv_in) {
    int n = blockIdx.x * 256 + threadIdx.x;
    if (n >= N_NODES) return;
    int di = 0;
#pragma unroll
    for (int b = 0; b < NB; ++b) {
        int key = b * NPAD + n;
        di += ecsbuf[key + 2] - ecsbuf[key + 1];
    }
    int a = deg_out[n]; if (a < 1) a = 1;
    if (di < 1) di = 1;
    inv_out[n] = 1.0f / sqrtf((float)a);
    inv_in[n]  = 1.0f / sqrtf((float)di);
}

// atomic on ecsbuf[1+key] doubles as cursor; post-fill it equals end(key)
__global__ void k_bucket(const int* __restrict__ ei, int* __restrict__ ecsbuf,
                         int* __restrict__ src_sorted) {
    int e = blockIdx.x * 256 + threadIdx.x;
    if (e < N_EDGES) {
        int s = ei[e], d = ei[N_EDGES + e];
        int p = atomicAdd(&ecsbuf[1 + (s >> 11) * NPAD + d], 1);
        src_sorted[p] = s;
    }
}

// ---------------- helpers ----------------

__device__ __forceinline__ float fast_tanh(float x) {
    float e = __expf(2.0f * x);
    float r = __builtin_amdgcn_rcpf(e + 1.0f);
    return 1.0f - 2.0f * r;
}

__device__ __forceinline__ unsigned short rne_bf16(float x) {
    unsigned u = __builtin_bit_cast(unsigned, x);
    return (unsigned short)((u + 0x7FFFu + ((u >> 16) & 1u)) >> 16);
}

__device__ __forceinline__ void split_bf16(float x, unsigned short& hi, unsigned short& lo) {
    hi = rne_bf16(x);
    float hf = __builtin_bit_cast(float, (unsigned)hi << 16);
    lo = rne_bf16(x - hf);
}

__device__ __forceinline__ f32x4 mfma16(short8 a, short8 b, f32x4 c) {
    return __builtin_amdgcn_mfma_f32_16x16x32_bf16(a, b, c, 0, 0, 0);
}

// ---------------- aggregation ----------------

// layer 0: gather x*inv_out (width 22), *inv_in, split to bf16 A (K pad 32).
// 16 threads/node; f2 11..15 write zero K-pad. Branch-free segment bounds.
__global__ void k_agg22_split(const float* __restrict__ x, const float* __restrict__ inv_out,
                              const int* __restrict__ ecsbuf, const int* __restrict__ srcs,
                              const float* __restrict__ inv_in,
                              unsigned short* __restrict__ A_hi, unsigned short* __restrict__ A_lo) {
    int idx = blockIdx.x * 256 + threadIdx.x;
    int n = idx >> 4, f2 = idx & 15;
    if (n >= N_NODES) return;
    float ax = 0.f, ay = 0.f;
    if (f2 <= 10) {
        const float2* xb = (const float2*)(x) + f2;
        for (int b = 0; b < NB; ++b) {
            int key = b * NPAD + n;
            int lo = ecsbuf[key];
            int hi = ecsbuf[key + 1];
            for (int e = lo; e < hi; ++e) {
                int s = srcs[e];
                float sc = inv_out[s];
                float2 v = xb[s * 11];
                ax += v.x * sc;
                ay += v.y * sc;
            }
        }
        float si = inv_in[n];
        ax *= si; ay *= si;
    }
    ushort2 h2, l2;
    split_bf16(ax, h2.x, l2.x);
    split_bf16(ay, h2.y, l2.y);
    *(ushort2*)&A_hi[n * 32 + f2 * 2] = h2;
    *(ushort2*)&A_lo[n * 32 + f2 * 2] = l2;
}

// width-220 bucketed gather with LDS accumulators.
// Wave owns 8 dst rows (LDS 8x224 f32, wave-private -> no barriers).
// Per bucket: the 8 segments are contiguous in src_sorted; bounds = 9
// consecutive ints (one load + readlanes). Merged range processed in chunks
// of 4 with 4 independent dwordx4 h-loads in flight (round-4 MLP restored);
// per-edge dst resolved by 7 scalar compares; accumulate = LDS b128 rmw.
__global__ __launch_bounds__(256) void k_agg220b(const float* __restrict__ h,
                                                 const int* __restrict__ ecsbuf,
                                                 const int* __restrict__ srcs,
                                                 const float* __restrict__ inv_in,
                                                 unsigned short* __restrict__ A_hi,
                                                 unsigned short* __restrict__ A_lo) {
    __shared__ float acc[32][224];     // 28.7 KB -> 5 blocks/CU
    int tid = threadIdx.x, lane = tid & 63, w = tid >> 6;
    int nbase = blockIdx.x * 32 + w * 8;
    float* accw = &acc[w * 8][0];
    int f4 = lane * 4;
    bool act = lane < 55;

    if (lane < 56) {                   // zero own rows (56*4 = 224 words)
        float4 z = {0.f, 0.f, 0.f, 0.f};
#pragma unroll
        for (int i = 0; i < 8; ++i) *(float4*)&accw[i * 224 + f4] = z;
    }

    const float* hb = h + f4;
    for (int b = 0; b < NB; ++b) {
        int kb = b * NPAD + nbase;
        int cv = (lane <= 8) ? ecsbuf[kb + lane] : 0;
        int c0 = __builtin_amdgcn_readlane(cv, 0);
        int c1 = __builtin_amdgcn_readlane(cv, 1);
        int c2 = __builtin_amdgcn_readlane(cv, 2);
        int c3 = __builtin_amdgcn_readlane(cv, 3);
        int c4 = __builtin_amdgcn_readlane(cv, 4);
        int c5 = __builtin_amdgcn_readlane(cv, 5);
        int c6 = __builtin_amdgcn_readlane(cv, 6);
        int c7 = __builtin_amdgcn_readlane(cv, 7);
        int c8 = __builtin_amdgcn_readlane(cv, 8);
#define SEG_OF(x) (((x) >= c1) + ((x) >= c2) + ((x) >= c3) + ((x) >= c4) + \
                   ((x) >= c5) + ((x) >= c6) + ((x) >= c7))
        for (int e = c0; e < c8; e += 4) {
            int m = c8 - e;            // >=1, uniform
            int sv = 0;
            if (lane < 4 && e + lane < c8) sv = srcs[e + lane];
            int s0 = __builtin_amdgcn_readlane(sv, 0);
            int s1 = __builtin_amdgcn_readlane(sv, 1);
            int s2 = __builtin_amdgcn_readlane(sv, 2);
            int s3 = __builtin_amdgcn_readlane(sv, 3);
            float4 v0 = {0,0,0,0}, v1 = {0,0,0,0}, v2 = {0,0,0,0}, v3 = {0,0,0,0};
            if (act) {
                v0 = *(const float4*)&hb[s0 * 220];
                if (m > 1) v1 = *(const float4*)&hb[s1 * 220];
                if (m > 2) v2 = *(const float4*)&hb[s2 * 220];
                if (m > 3) v3 = *(const float4*)&hb[s3 * 220];
            }
            if (act) {
                {
                    int i0 = SEG_OF(e);
                    float4 t = *(float4*)&accw[i0 * 224 + f4];
                    t.x += v0.x; t.y += v0.y; t.z += v0.z; t.w += v0.w;
                    *(float4*)&accw[i0 * 224 + f4] = t;
                }
                if (m > 1) {
                    int i1 = SEG_OF(e + 1);
                    float4 t = *(float4*)&accw[i1 * 224 + f4];
                    t.x += v1.x; t.y += v1.y; t.z += v1.z; t.w += v1.w;
                    *(float4*)&accw[i1 * 224 + f4] = t;
                }
                if (m > 2) {
                    int i2 = SEG_OF(e + 2);
                    float4 t = *(float4*)&accw[i2 * 224 + f4];
                    t.x += v2.x; t.y += v2.y; t.z += v2.z; t.w += v2.w;
                    *(float4*)&accw[i2 * 224 + f4] = t;
                }
                if (m > 3) {
                    int i3 = SEG_OF(e + 3);
                    float4 t = *(float4*)&accw[i3 * 224 + f4];
                    t.x += v3.x; t.y += v3.y; t.z += v3.z; t.w += v3.w;
                    *(float4*)&accw[i3 * 224 + f4] = t;
                }
            }
        }
#undef SEG_OF
    }

    // epilogue: *inv_in, split bf16 hi/lo, write A (stride 224; lane 55 = K-pad)
    if (lane >= 56) return;
#pragma unroll
    for (int i = 0; i < 8; ++i) {
        int n = nbase + i;
        if (n >= N_NODES) continue;
        size_t ob = (size_t)n * 224 + f4;
        if (act) {
            float sc = inv_in[n];
            float4 t = *(float4*)&accw[i * 224 + f4];
            ushort4 h4, l4;
            split_bf16(t.x * sc, h4.x, l4.x);
            split_bf16(t.y * sc, h4.y, l4.y);
            split_bf16(t.z * sc, h4.z, l4.z);
            split_bf16(t.w * sc, h4.w, l4.w);
            *(ushort4*)&A_hi[ob] = h4;
            *(ushort4*)&A_lo[ob] = l4;
        } else {
            ushort4 z = {0, 0, 0, 0};
            *(ushort4*)&A_hi[ob] = z;
            *(ushort4*)&A_lo[ob] = z;
        }
    }
}

// layer 3: gather tmp10 (width 10, 2 MB -> L2-resident), *inv_in + bias -> d_out
__global__ void k_agg10_epi(const float* __restrict__ tmp, const int* __restrict__ ecsbuf,
                            const int* __restrict__ srcs, const float* __restrict__ inv_in,
                            const float* __restrict__ bias, float* __restrict__ out) {
    int idx = blockIdx.x * 256 + threadIdx.x;
    if (idx >= N_NODES * 5) return;
    int n = idx / 5;
    int f2 = idx - n * 5;
    const float2* tb = (const float2*)(tmp) + f2;
    float ax = 0.f, ay = 0.f;
    for (int b = 0; b < NB; ++b) {
        int key = b * NPAD + n;
        int lo = ecsbuf[key];
        int hi = ecsbuf[key + 1];
        for (int e = lo; e < hi; ++e) {
            float2 v = tb[srcs[e] * 5];
            ax += v.x;
            ay += v.y;
        }
    }
    float si = inv_in[n];
    float2 o;
    o.x = ax * si + bias[f2 * 2];
    o.y = ay * si + bias[f2 * 2 + 1];
    *(float2*)&out[n * 10 + f2 * 2] = o;
}

// ---------------- weight split (all three in one launch) ----------------

__device__ __forceinline__ void wsplit_one(const float* __restrict__ W, int KIN, int LDA,
                                           unsigned short* __restrict__ WT_hi,
                                           unsigned short* __restrict__ WT_lo, int idx) {
    int n = idx / LDA;
    int k = idx - n * LDA;
    float v = (n < 220 && k < KIN) ? W[k * 220 + n] : 0.f;
    unsigned short hi, lo;
    split_bf16(v, hi, lo);
    WT_hi[idx] = hi;
    WT_lo[idx] = lo;
}

__global__ void k_wsplit_all(const float* __restrict__ W0, const float* __restrict__ W1,
                             const float* __restrict__ W2,
                             unsigned short* __restrict__ wt0h, unsigned short* __restrict__ wt0l,
                             unsigned short* __restrict__ wt1h, unsigned short* __restrict__ wt1l,
                             unsigned short* __restrict__ wt2h, unsigned short* __restrict__ wt2l) {
    int bx = blockIdx.x;
    if (bx < 28) {
        int idx = bx * 256 + threadIdx.x;          // 224*32 = 7168
        if (idx < 224 * 32) wsplit_one(W0, 22, 32, wt0h, wt0l, idx);
    } else if (bx < 224) {
        int idx = (bx - 28) * 256 + threadIdx.x;   // 224*224 = 50176
        wsplit_one(W1, 220, 224, wt1h, wt1l, idx);
    } else {
        int idx = (bx - 224) * 256 + threadIdx.x;
        wsplit_one(W2, 220, 224, wt2h, wt2l, idx);
    }
}

// ---------------- MFMA split-bf16 GEMM ----------------
// D = A@W via A_hi*W_hi + A_hi*W_lo + A_lo*W_hi (~fp32 precision).
// out[n][j] = post[n] * tanh(D + bias); inv_in pre-folded into A.
template <int KSTEPS, int LDA>
__global__ __launch_bounds__(256) void k_gemm_mfma(const unsigned short* __restrict__ A_hi,
                                                   const unsigned short* __restrict__ A_lo,
                                                   const unsigned short* __restrict__ WT_hi,
                                                   const unsigned short* __restrict__ WT_lo,
                                                   const float* __restrict__ bias,
                                                   const float* __restrict__ post,
                                                   float* __restrict__ out) {
    int tid = threadIdx.x;
    int l = tid & 63, w = tid >> 6;
    int lrow = l & 15, q = l >> 4;
    int rtile = blockIdx.x * 64 + w * 16;

    const unsigned short* pah = A_hi + (size_t)(rtile + lrow) * LDA + q * 8;
    const unsigned short* pal = A_lo + (size_t)(rtile + lrow) * LDA + q * 8;

    f32x4 acc[14];
#pragma unroll
    for (int ct = 0; ct < 14; ++ct) acc[ct] = (f32x4){0.f, 0.f, 0.f, 0.f};

#pragma unroll
    for (int ks = 0; ks < KSTEPS; ++ks) {
        int k0 = ks * 32;
        short8 ah = *(const short8*)(const void*)(pah + k0);
        short8 al = *(const short8*)(const void*)(pal + k0);
#pragma unroll
        for (int ct = 0; ct < 14; ++ct) {
            size_t boff = (size_t)(ct * 16 + lrow) * LDA + q * 8 + k0;
            short8 bh = *(const short8*)(const void*)(WT_hi + boff);
            short8 bl = *(const short8*)(const void*)(WT_lo + boff);
            acc[ct] = mfma16(ah, bh, acc[ct]);
            acc[ct] = mfma16(ah, bl, acc[ct]);
            acc[ct] = mfma16(al, bh, acc[ct]);
        }
    }

    float pv[4];
#pragma unroll
    for (int r = 0; r < 4; ++r) {
        int row = rtile + q * 4 + r;
        pv[r] = (row < N_NODES) ? post[row] : 0.f;
    }
#pragma unroll
    for (int ct = 0; ct < 14; ++ct) {
        int col = ct * 16 + lrow;
        if (col >= 220) continue;
        float bv = bias[col];
#pragma unroll
        for (int r = 0; r < 4; ++r) {
            int row = rtile + q * 4 + r;
            if (row < N_NODES)
                out[(size_t)row * 220 + col] = pv[r] * fast_tanh(acc[ct][r] + bv);
        }
    }
}

// tmp10 = h @ W3 — thread per node, full row (44 MB total, vs 440 MB for the
// old 10-threads/row form). W3 reads are wave-uniform -> scalar loads.
__global__ __launch_bounds__(256) void k_w3(const float* __restrict__ h,
                                            const float* __restrict__ W3,
                                            float* __restrict__ tmp) {
    int n = blockIdx.x * 256 + threadIdx.x;
    if (n >= N_NODES) return;
    float a[10];
#pragma unroll
    for (int j = 0; j < 10; ++j) a[j] = 0.f;
    const float4* hr = (const float4*)&h[(size_t)n * 220];
#pragma unroll 5
    for (int k4 = 0; k4 < 55; ++k4) {
        float4 v = hr[k4];
        const float* wk = &W3[k4 * 40];
#pragma unroll
        for (int j = 0; j < 10; ++j)
            a[j] += v.x * wk[j] + v.y * wk[10 + j] + v.z * wk[20 + j] + v.w * wk[30 + j];
    }
#pragma unroll
    for (int j2 = 0; j2 < 5; ++j2) {
        float2 o = {a[2 * j2], a[2 * j2 + 1]};
        *(float2*)&tmp[(size_t)n * 10 + j2 * 2] = o;
    }
}

// ---------------- launch ----------------

extern "C" void kernel_launch(void* const* d_in, const int* in_sizes, int n_in,
                              void* d_out, int out_size, void* d_ws, size_t ws_size,
                              hipStream_t stream) {
    const float* x  = (const float*)d_in[0];
    const float* W0 = (const float*)d_in[1];
    const float* b0 = (const float*)d_in[2];
    const float* W1 = (const float*)d_in[3];
    const float* b1 = (const float*)d_in[4];
    const float* W2 = (const float*)d_in[5];
    const float* b2 = (const float*)d_in[6];
    const float* W3 = (const float*)d_in[7];
    const float* b3 = (const float*)d_in[8];
    const int*   ei = (const int*)d_in[9];
    float* out = (float*)d_out;

    int* ws = (int*)d_ws;
    // word offsets
    int* ecsbuf     = ws + 0;               // NKEY+2 -> pad 1254656
    int* deg_out    = ws + 1254656;         // 50176
    int* bsumA      = ws + 1304832;         // 5120 (4900 used)
    float* inv_out  = (float*)(ws + 1309952);
    float* inv_in   = (float*)(ws + 1360128);
    int* src_sorted = ws + 1410304;         // 800000
    unsigned short* wt0h = (unsigned short*)(ws + 2210304);   // 3584 words
    unsigned short* wt0l = (unsigned short*)(ws + 2213888);
    unsigned short* wt1h = (unsigned short*)(ws + 2217472);   // 25088 words
    unsigned short* wt1l = (unsigned short*)(ws + 2242560);
    unsigned short* wt2h = (unsigned short*)(ws + 2267648);
    unsigned short* wt2l = (unsigned short*)(ws + 2292736);
    unsigned short* ahi  = (unsigned short*)(ws + 2317824);   // 50176*224 bf16 = 5619712 w
    unsigned short* alo  = (unsigned short*)(ws + 7937536);
    float* tmp10 = (float*)ahi;             // layer-3 alias (ahi dead by then)
    float* hbuf  = (float*)(ws + 13557248); // 50000*220

    // independent of CSR: weight splits first
    k_wsplit_all<<<420, 256, 0, stream>>>(W0, W1, W2, wt0h, wt0l, wt1h, wt1l, wt2h, wt2l);

    // zero ecsbuf + deg_out (contiguous)
    hipMemsetAsync(ws, 0, (size_t)1304832 * sizeof(int), stream);

    k_hist<<<(N_EDGES + 255) / 256, 256, 0, stream>>>(ei, deg_out, ecsbuf);
    k_scan1<<<4900, 256, 0, stream>>>(ecsbuf + 1, ecsbuf + 1, bsumA, NKEY);
    k_scan_mid<<<1, 256, 0, stream>>>(bsumA, 4900);
    k_scan3<<<4900, 256, 0, stream>>>(ecsbuf + 1, bsumA, NKEY);
    k_invsqrt<<<196, 256, 0, stream>>>(deg_out, ecsbuf, inv_out, inv_in);
    k_bucket<<<(N_EDGES + 255) / 256, 256, 0, stream>>>(ei, ecsbuf, src_sorted);

    int mfma_grid = (N_NODES + 63) / 64;     // 782
    int agg_grid  = (N_NODES + 31) / 32;     // 1563 (co-resident for bucket phasing)

    // ---- layer 0
    k_agg22_split<<<(N_NODES * 16 + 255) / 256, 256, 0, stream>>>(
        x, inv_out, ecsbuf, src_sorted, inv_in, ahi, alo);
    k_gemm_mfma<1, 32><<<mfma_grid, 256, 0, stream>>>(ahi, alo, wt0h, wt0l, b0, inv_out, hbuf);

    // ---- layer 1
    k_agg220b<<<agg_grid, 256, 0, stream>>>(hbuf, ecsbuf, src_sorted, inv_in, ahi, alo);
    k_gemm_mfma<7, 224><<<mfma_grid, 256, 0, stream>>>(ahi, alo, wt1h, wt1l, b1, inv_out, hbuf);

    // ---- layer 2
    k_agg220b<<<agg_grid, 256, 0, stream>>>(hbuf, ecsbuf, src_sorted, inv_in, ahi, alo);
    k_gemm_mfma<7, 224><<<mfma_grid, 256, 0, stream>>>(ahi, alo, wt2h, wt2l, b2, inv_out, hbuf);

    // ---- layer 3
    k_w3<<<196, 256, 0, stream>>>(hbuf, W3, tmp10);
    k_agg10_epi<<<(N_NODES * 5 + 255) / 256, 256, 0, stream>>>(
        tmp10, ecsbuf, src_sorted, inv_in, b3, out);
}

// Round 8
// 675.217 us; speedup vs baseline: 1.3584x; 1.2010x over previous
//
#include <hip/hip_runtime.h>
#include <math.h>

#define N_NODES 50000
#define N_EDGES 800000
#define NPAD 50176
// ecsbuf layout (NPAD+pad ints, ecsbuf[0]=0 forever): counts/prefix/cursor at ecsbuf[1+d].
//   post-scan: start(d) = ecsbuf[1+d] (exclusive prefix)
//   post-fill: ecsbuf[1+d] = end(d)  => start(d) = ecsbuf[d], end(d) = ecsbuf[d+1]

typedef __attribute__((ext_vector_type(8))) short short8;
typedef __attribute__((ext_vector_type(4))) float f32x4;

// ---------------- CSR build ----------------

__global__ void k_hist(const int* __restrict__ ei, int* __restrict__ deg_out,
                       int* __restrict__ ecsbuf) {
    int e = blockIdx.x * 256 + threadIdx.x;
    if (e < N_EDGES) {
        atomicAdd(&deg_out[ei[e]], 1);
        atomicAdd(&ecsbuf[1 + ei[N_EDGES + e]], 1);
    }
}

__global__ void k_scan1(const int* __restrict__ in, int* __restrict__ out,
                        int* __restrict__ bsum, int n) {
    __shared__ int s[256];
    int i = blockIdx.x * 256 + threadIdx.x;
    int v = (i < n) ? in[i] : 0;
    s[threadIdx.x] = v;
    __syncthreads();
    for (int off = 1; off < 256; off <<= 1) {
        int t = (threadIdx.x >= off) ? s[threadIdx.x - off] : 0;
        __syncthreads();
        s[threadIdx.x] += t;
        __syncthreads();
    }
    if (i < n) out[i] = s[threadIdx.x] - v;   // exclusive
    if (threadIdx.x == 255 && bsum) bsum[blockIdx.x] = s[255];
}

// single-block serial-chunk exclusive scan
__global__ void k_scan_mid(int* __restrict__ a, int n) {
    __shared__ int s[256];
    __shared__ int carry;
    if (threadIdx.x == 0) carry = 0;
    for (int base = 0; base < n; base += 256) {
        int i = base + threadIdx.x;
        int v = (i < n) ? a[i] : 0;
        s[threadIdx.x] = v;
        __syncthreads();
        for (int off = 1; off < 256; off <<= 1) {
            int t = (threadIdx.x >= off) ? s[threadIdx.x - off] : 0;
            __syncthreads();
            s[threadIdx.x] += t;
            __syncthreads();
        }
        int c = carry;
        if (i < n) a[i] = s[threadIdx.x] - v + c;
        __syncthreads();
        if (threadIdx.x == 0) carry = c + s[255];
        __syncthreads();
    }
}

__global__ void k_scan3(int* __restrict__ out, const int* __restrict__ bscan, int n) {
    int i = blockIdx.x * 256 + threadIdx.x;
    if (i < n) out[i] += bscan[blockIdx.x];
}

// pre-fill: deg_in(n) = ecsbuf[n+2] - ecsbuf[n+1]
__global__ void k_invsqrt(const int* __restrict__ deg_out, const int* __restrict__ ecsbuf,
                          float* __restrict__ inv_out, float* __restrict__ inv_in) {
    int n = blockIdx.x * 256 + threadIdx.x;
    if (n >= N_NODES) return;
    int di = ecsbuf[n + 2] - ecsbuf[n + 1];
    int a = deg_out[n]; if (a < 1) a = 1;
    if (di < 1) di = 1;
    inv_out[n] = 1.0f / sqrtf((float)a);
    inv_in[n]  = 1.0f / sqrtf((float)di);
}

// atomic on ecsbuf[1+d] doubles as cursor; post-fill it equals end(d)
__global__ void k_bucket(const int* __restrict__ ei, int* __restrict__ ecsbuf,
                         int* __restrict__ src_sorted) {
    int e = blockIdx.x * 256 + threadIdx.x;
    if (e < N_EDGES) {
        int s = ei[e], d = ei[N_EDGES + e];
        int p = atomicAdd(&ecsbuf[1 + d], 1);
        src_sorted[p] = s;
    }
}

// ---------------- helpers ----------------

__device__ __forceinline__ float fast_tanh(float x) {
    float e = __expf(2.0f * x);
    float r = __builtin_amdgcn_rcpf(e + 1.0f);
    return 1.0f - 2.0f * r;
}

__device__ __forceinline__ unsigned short rne_bf16(float x) {
    unsigned u = __builtin_bit_cast(unsigned, x);
    return (unsigned short)((u + 0x7FFFu + ((u >> 16) & 1u)) >> 16);
}

__device__ __forceinline__ void split_bf16(float x, unsigned short& hi, unsigned short& lo) {
    hi = rne_bf16(x);
    float hf = __builtin_bit_cast(float, (unsigned)hi << 16);
    lo = rne_bf16(x - hf);
}

__device__ __forceinline__ f32x4 mfma16(short8 a, short8 b, f32x4 c) {
    return __builtin_amdgcn_mfma_f32_16x16x32_bf16(a, b, c, 0, 0, 0);
}

// ---------------- aggregation ----------------

// layer 0: gather x*inv_out (width 22), *inv_in, split to bf16 A (K pad 32).
// 16 threads/node; f2 slots 11..15 write zero K-pad.
__global__ void k_agg22_split(const float* __restrict__ x, const float* __restrict__ inv_out,
                              const int* __restrict__ ecsbuf, const int* __restrict__ srcs,
                              const float* __restrict__ inv_in,
                              unsigned short* __restrict__ A_hi, unsigned short* __restrict__ A_lo) {
    int idx = blockIdx.x * 256 + threadIdx.x;
    int n = idx >> 4, f2 = idx & 15;
    if (n >= N_NODES) return;
    float ax = 0.f, ay = 0.f;
    if (f2 <= 10) {
        const float2* xb = (const float2*)(x) + f2;
        int e = ecsbuf[n], end = ecsbuf[n + 1];
        for (; e + 1 < end; e += 2) {
            int s0 = srcs[e], s1 = srcs[e + 1];
            float c0 = inv_out[s0], c1 = inv_out[s1];
            float2 v0 = xb[s0 * 11], v1 = xb[s1 * 11];
            ax += v0.x * c0 + v1.x * c1;
            ay += v0.y * c0 + v1.y * c1;
        }
        if (e < end) {
            int s0 = srcs[e];
            float c0 = inv_out[s0];
            float2 v0 = xb[s0 * 11];
            ax += v0.x * c0;
            ay += v0.y * c0;
        }
        float si = inv_in[n];
        ax *= si; ay *= si;
    }
    ushort2 h2, l2;
    split_bf16(ax, h2.x, l2.x);
    split_bf16(ay, h2.y, l2.y);
    *(ushort2*)&A_hi[n * 32 + f2 * 2] = h2;
    *(ushort2*)&A_lo[n * 32 + f2 * 2] = l2;
}

// width-220 gather + fused (sum*inv_in) -> split bf16 A (stride 224; lane 55 = K-pad).
// One node per 64-lane group; lanes 0..54 own 4 features (float4 row gather).
// 8 independent dwordx4 loads in flight per iteration.
// FETCH ~357 MB = compulsory per-XCD first-touch of h (8 x 44 MB); L3 serves re-reads.
__global__ __launch_bounds__(256) void k_agg220_split(const float* __restrict__ h,
                                                      const int* __restrict__ ecsbuf,
                                                      const int* __restrict__ srcs,
                                                      const float* __restrict__ inv_in,
                                                      unsigned short* __restrict__ A_hi,
                                                      unsigned short* __restrict__ A_lo) {
    int lane = threadIdx.x & 63;
    int n = blockIdx.x * 4 + (threadIdx.x >> 6);
    if (n >= N_NODES || lane >= 56) return;   // no barriers; early-exit safe
    size_t ob = (size_t)n * 224 + lane * 4;
    if (lane == 55) {                          // K-pad columns 220..223 = 0
        ushort4 z = {0, 0, 0, 0};
        *(ushort4*)&A_hi[ob] = z;
        *(ushort4*)&A_lo[ob] = z;
        return;
    }
    int f4 = lane * 4;
    const float* hb = h + f4;
    int e = ecsbuf[n], end = ecsbuf[n + 1];
    float4 a0 = {0,0,0,0}, a1 = {0,0,0,0}, a2 = {0,0,0,0}, a3 = {0,0,0,0};
    for (; e + 7 < end; e += 8) {
        int s0 = srcs[e],     s1 = srcs[e + 1], s2 = srcs[e + 2], s3 = srcs[e + 3];
        int s4 = srcs[e + 4], s5 = srcs[e + 5], s6 = srcs[e + 6], s7 = srcs[e + 7];
        float4 v0 = *(const float4*)&hb[s0 * 220];
        float4 v1 = *(const float4*)&hb[s1 * 220];
        float4 v2 = *(const float4*)&hb[s2 * 220];
        float4 v3 = *(const float4*)&hb[s3 * 220];
        float4 v4 = *(const float4*)&hb[s4 * 220];
        float4 v5 = *(const float4*)&hb[s5 * 220];
        float4 v6 = *(const float4*)&hb[s6 * 220];
        float4 v7 = *(const float4*)&hb[s7 * 220];
        a0.x += v0.x; a0.y += v0.y; a0.z += v0.z; a0.w += v0.w;
        a1.x += v1.x; a1.y += v1.y; a1.z += v1.z; a1.w += v1.w;
        a2.x += v2.x; a2.y += v2.y; a2.z += v2.z; a2.w += v2.w;
        a3.x += v3.x; a3.y += v3.y; a3.z += v3.z; a3.w += v3.w;
        a0.x += v4.x; a0.y += v4.y; a0.z += v4.z; a0.w += v4.w;
        a1.x += v5.x; a1.y += v5.y; a1.z += v5.z; a1.w += v5.w;
        a2.x += v6.x; a2.y += v6.y; a2.z += v6.z; a2.w += v6.w;
        a3.x += v7.x; a3.y += v7.y; a3.z += v7.z; a3.w += v7.w;
    }
    for (; e + 3 < end; e += 4) {
        int s0 = srcs[e], s1 = srcs[e + 1], s2 = srcs[e + 2], s3 = srcs[e + 3];
        float4 v0 = *(const float4*)&hb[s0 * 220];
        float4 v1 = *(const float4*)&hb[s1 * 220];
        float4 v2 = *(const float4*)&hb[s2 * 220];
        float4 v3 = *(const float4*)&hb[s3 * 220];
        a0.x += v0.x; a0.y += v0.y; a0.z += v0.z; a0.w += v0.w;
        a1.x += v1.x; a1.y += v1.y; a1.z += v1.z; a1.w += v1.w;
        a2.x += v2.x; a2.y += v2.y; a2.z += v2.z; a2.w += v2.w;
        a3.x += v3.x; a3.y += v3.y; a3.z += v3.z; a3.w += v3.w;
    }
    for (; e < end; ++e) {
        float4 v = *(const float4*)&hb[srcs[e] * 220];
        a0.x += v.x; a0.y += v.y; a0.z += v.z; a0.w += v.w;
    }
    float sc = inv_in[n];
    float4 t;
    t.x = ((a0.x + a1.x) + (a2.x + a3.x)) * sc;
    t.y = ((a0.y + a1.y) + (a2.y + a3.y)) * sc;
    t.z = ((a0.z + a1.z) + (a2.z + a3.z)) * sc;
    t.w = ((a0.w + a1.w) + (a2.w + a3.w)) * sc;
    ushort4 h4, l4;
    split_bf16(t.x, h4.x, l4.x);
    split_bf16(t.y, h4.y, l4.y);
    split_bf16(t.z, h4.z, l4.z);
    split_bf16(t.w, h4.w, l4.w);
    *(ushort4*)&A_hi[ob] = h4;
    *(ushort4*)&A_lo[ob] = l4;
}

// layer 3: gather tmp10 (width 10, 2 MB -> L2-resident), *inv_in + bias -> d_out
__global__ void k_agg10_epi(const float* __restrict__ tmp, const int* __restrict__ ecsbuf,
                            const int* __restrict__ srcs, const float* __restrict__ inv_in,
                            const float* __restrict__ bias, float* __restrict__ out) {
    int idx = blockIdx.x * 256 + threadIdx.x;
    if (idx >= N_NODES * 5) return;
    int n = idx / 5;
    int f2 = idx - n * 5;
    const float2* tb = (const float2*)(tmp) + f2;
    float ax = 0.f, ay = 0.f;
    int e = ecsbuf[n], end = ecsbuf[n + 1];
    for (; e + 1 < end; e += 2) {
        float2 v0 = tb[srcs[e] * 5];
        float2 v1 = tb[srcs[e + 1] * 5];
        ax += v0.x + v1.x;
        ay += v0.y + v1.y;
    }
    if (e < end) {
        float2 v0 = tb[srcs[e] * 5];
        ax += v0.x;
        ay += v0.y;
    }
    float si = inv_in[n];
    float2 o;
    o.x = ax * si + bias[f2 * 2];
    o.y = ay * si + bias[f2 * 2 + 1];
    *(float2*)&out[n * 10 + f2 * 2] = o;
}

// ---------------- weight split (all three in one launch) ----------------

__device__ __forceinline__ void wsplit_one(const float* __restrict__ W, int KIN, int LDA,
                                           unsigned short* __restrict__ WT_hi,
                                           unsigned short* __restrict__ WT_lo, int idx) {
    int n = idx / LDA;
    int k = idx - n * LDA;
    float v = (n < 220 && k < KIN) ? W[k * 220 + n] : 0.f;
    unsigned short hi, lo;
    split_bf16(v, hi, lo);
    WT_hi[idx] = hi;
    WT_lo[idx] = lo;
}

__global__ void k_wsplit_all(const float* __restrict__ W0, const float* __restrict__ W1,
                             const float* __restrict__ W2,
                             unsigned short* __restrict__ wt0h, unsigned short* __restrict__ wt0l,
                             unsigned short* __restrict__ wt1h, unsigned short* __restrict__ wt1l,
                             unsigned short* __restrict__ wt2h, unsigned short* __restrict__ wt2l) {
    int bx = blockIdx.x;
    if (bx < 28) {
        int idx = bx * 256 + threadIdx.x;          // 224*32 = 7168
        if (idx < 224 * 32) wsplit_one(W0, 22, 32, wt0h, wt0l, idx);
    } else if (bx < 224) {
        int idx = (bx - 28) * 256 + threadIdx.x;   // 224*224 = 50176
        wsplit_one(W1, 220, 224, wt1h, wt1l, idx);
    } else {
        int idx = (bx - 224) * 256 + threadIdx.x;
        wsplit_one(W2, 220, 224, wt2h, wt2l, idx);
    }
}

// ---------------- MFMA split-bf16 GEMM ----------------
// D = A@W via A_hi*W_hi + A_hi*W_lo + A_lo*W_hi (~fp32 precision).
// out[n][j] = post[n] * tanh(D + bias); inv_in pre-folded into A.
template <int KSTEPS, int LDA>
__global__ __launch_bounds__(256) void k_gemm_mfma(const unsigned short* __restrict__ A_hi,
                                                   const unsigned short* __restrict__ A_lo,
                                                   const unsigned short* __restrict__ WT_hi,
                                                   const unsigned short* __restrict__ WT_lo,
                                                   const float* __restrict__ bias,
                                                   const float* __restrict__ post,
                                                   float* __restrict__ out) {
    int tid = threadIdx.x;
    int l = tid & 63, w = tid >> 6;
    int lrow = l & 15, q = l >> 4;
    int rtile = blockIdx.x * 64 + w * 16;

    const unsigned short* pah = A_hi + (size_t)(rtile + lrow) * LDA + q * 8;
    const unsigned short* pal = A_lo + (size_t)(rtile + lrow) * LDA + q * 8;

    f32x4 acc[14];
#pragma unroll
    for (int ct = 0; ct < 14; ++ct) acc[ct] = (f32x4){0.f, 0.f, 0.f, 0.f};

#pragma unroll
    for (int ks = 0; ks < KSTEPS; ++ks) {
        int k0 = ks * 32;
        short8 ah = *(const short8*)(const void*)(pah + k0);
        short8 al = *(const short8*)(const void*)(pal + k0);
#pragma unroll
        for (int ct = 0; ct < 14; ++ct) {
            size_t boff = (size_t)(ct * 16 + lrow) * LDA + q * 8 + k0;
            short8 bh = *(const short8*)(const void*)(WT_hi + boff);
            short8 bl = *(const short8*)(const void*)(WT_lo + boff);
            acc[ct] = mfma16(ah, bh, acc[ct]);
            acc[ct] = mfma16(ah, bl, acc[ct]);
            acc[ct] = mfma16(al, bh, acc[ct]);
        }
    }

    float pv[4];
#pragma unroll
    for (int r = 0; r < 4; ++r) {
        int row = rtile + q * 4 + r;
        pv[r] = (row < N_NODES) ? post[row] : 0.f;
    }
#pragma unroll
    for (int ct = 0; ct < 14; ++ct) {
        int col = ct * 16 + lrow;
        if (col >= 220) continue;
        float bv = bias[col];
#pragma unroll
        for (int r = 0; r < 4; ++r) {
            int row = rtile + q * 4 + r;
            if (row < N_NODES)
                out[(size_t)row * 220 + col] = pv[r] * fast_tanh(acc[ct][r] + bv);
        }
    }
}

// tmp10 = h @ W3 — thread per node, full row. W3 reads are wave-uniform.
__global__ __launch_bounds__(256) void k_w3(const float* __restrict__ h,
                                            const float* __restrict__ W3,
                                            float* __restrict__ tmp) {
    int n = blockIdx.x * 256 + threadIdx.x;
    if (n >= N_NODES) return;
    float a[10];
#pragma unroll
    for (int j = 0; j < 10; ++j) a[j] = 0.f;
    const float4* hr = (const float4*)&h[(size_t)n * 220];
#pragma unroll 5
    for (int k4 = 0; k4 < 55; ++k4) {
        float4 v = hr[k4];
        const float* wk = &W3[k4 * 40];
#pragma unroll
        for (int j = 0; j < 10; ++j)
            a[j] += v.x * wk[j] + v.y * wk[10 + j] + v.z * wk[20 + j] + v.w * wk[30 + j];
    }
#pragma unroll
    for (int j2 = 0; j2 < 5; ++j2) {
        float2 o = {a[2 * j2], a[2 * j2 + 1]};
        *(float2*)&tmp[(size_t)n * 10 + j2 * 2] = o;
    }
}

// ---------------- launch ----------------

extern "C" void kernel_launch(void* const* d_in, const int* in_sizes, int n_in,
                              void* d_out, int out_size, void* d_ws, size_t ws_size,
                              hipStream_t stream) {
    const float* x  = (const float*)d_in[0];
    const float* W0 = (const float*)d_in[1];
    const float* b0 = (const float*)d_in[2];
    const float* W1 = (const float*)d_in[3];
    const float* b1 = (const float*)d_in[4];
    const float* W2 = (const float*)d_in[5];
    const float* b2 = (const float*)d_in[6];
    const float* W3 = (const float*)d_in[7];
    const float* b3 = (const float*)d_in[8];
    const int*   ei = (const int*)d_in[9];
    float* out = (float*)d_out;

    int* ws = (int*)d_ws;
    // word offsets. NOTE: wt1/wt2 are 224*224 USHORTS = 50176 ushorts = 25088 WORDS
    // each (round-7 bug: spaced them 12544 words -> overlap corrupted W1/W2).
    int* ecsbuf     = ws + 0;               // 50432 (50002 used; [0]=0)
    int* deg_out    = ws + 50432;           // 50176
    int* bsumA      = ws + 100608;          // 256 (196 used)
    float* inv_out  = (float*)(ws + 100864);
    float* inv_in   = (float*)(ws + 151040);
    int* src_sorted = ws + 201216;          // 800000
    unsigned short* wt0h = (unsigned short*)(ws + 1001216);   // 3584 words (224*32 us)
    unsigned short* wt0l = (unsigned short*)(ws + 1004800);   // 3584 words
    unsigned short* wt1h = (unsigned short*)(ws + 1008384);   // 25088 words (224*224 us)
    unsigned short* wt1l = (unsigned short*)(ws + 1033472);   // 25088 words
    unsigned short* wt2h = (unsigned short*)(ws + 1058560);   // 25088 words
    unsigned short* wt2l = (unsigned short*)(ws + 1083648);   // 25088 words
    unsigned short* ahi  = (unsigned short*)(ws + 1108736);   // 50176*224 us = 5619712 w
    unsigned short* alo  = (unsigned short*)(ws + 6728448);   // 5619712 w
    float* tmp10 = (float*)ahi;             // layer-3 alias (ahi dead by then)
    float* hbuf  = (float*)(ws + 12348160); // 50000*220 = 11000000 w

    // independent of CSR: weight splits first
    k_wsplit_all<<<420, 256, 0, stream>>>(W0, W1, W2, wt0h, wt0l, wt1h, wt1l, wt2h, wt2l);

    // zero ecsbuf + deg_out (contiguous)
    hipMemsetAsync(ws, 0, (size_t)100608 * sizeof(int), stream);

    k_hist<<<(N_EDGES + 255) / 256, 256, 0, stream>>>(ei, deg_out, ecsbuf);
    k_scan1<<<196, 256, 0, stream>>>(ecsbuf + 1, ecsbuf + 1, bsumA, NPAD);
    k_scan_mid<<<1, 256, 0, stream>>>(bsumA, 196);
    k_scan3<<<196, 256, 0, stream>>>(ecsbuf + 1, bsumA, NPAD);
    k_invsqrt<<<196, 256, 0, stream>>>(deg_out, ecsbuf, inv_out, inv_in);
    k_bucket<<<(N_EDGES + 255) / 256, 256, 0, stream>>>(ei, ecsbuf, src_sorted);

    int mfma_grid = (N_NODES + 63) / 64;     // 782
    int agg_grid  = (N_NODES + 3) / 4;       // 12500

    // ---- layer 0
    k_agg22_split<<<(N_NODES * 16 + 255) / 256, 256, 0, stream>>>(
        x, inv_out, ecsbuf, src_sorted, inv_in, ahi, alo);
    k_gemm_mfma<1, 32><<<mfma_grid, 256, 0, stream>>>(ahi, alo, wt0h, wt0l, b0, inv_out, hbuf);

    // ---- layer 1
    k_agg220_split<<<agg_grid, 256, 0, stream>>>(hbuf, ecsbuf, src_sorted, inv_in, ahi, alo);
    k_gemm_mfma<7, 224><<<mfma_grid, 256, 0, stream>>>(ahi, alo, wt1h, wt1l, b1, inv_out, hbuf);

    // ---- layer 2
    k_agg220_split<<<agg_grid, 256, 0, stream>>>(hbuf, ecsbuf, src_sorted, inv_in, ahi, alo);
    k_gemm_mfma<7, 224><<<mfma_grid, 256, 0, stream>>>(ahi, alo, wt2h, wt2l, b2, inv_out, hbuf);

    // ---- layer 3
    k_w3<<<196, 256, 0, stream>>>(hbuf, W3, tmp10);
    k_agg10_epi<<<(N_NODES * 5 + 255) / 256, 256, 0, stream>>>(
        tmp10, ecsbuf, src_sorted, inv_in, b3, out);
}